// Round 3
// baseline (438.174 us; speedup 1.0000x reference)
//
#include <hip/hip_runtime.h>

#define N_NODES 50000
#define N_EDGES 640000

// workspace layout (float/int offsets, 4B units)
#define OFF_HTMP     0          // float[6400000]
#define OFF_DEG      6400000    // int[50000]
#define OFF_ROWSTART 6450000    // int[50001]
#define OFF_CURSOR   6500016    // int[50000]
#define OFF_DINV     6550016    // float[50000]
#define OFF_E        6600016    // float[50000]
#define OFF_Q        6650016    // float[50000]
#define OFF_SCAL     6700016    // [0]=EminBits [1]=S0 [2]=S1
#define OFF_BLKSUM   6700020    // int[256]
#define OFF_ESRC     6700276    // int[640000] CSR-bucketed source ids
#define OFF_EPART    7340276    // float[8*50000] per-chunk energy partials

__global__ __launch_bounds__(256) void k_init(float* ws) {
    int i = blockIdx.x * 256 + threadIdx.x;
    if (i < N_NODES) ((int*)(ws + OFF_DEG))[i] = 0;
    if (i == 0) {
        ((int*)(ws + OFF_SCAL))[0] = 0x7F7FFFFF;  // FLT_MAX bits
        ws[OFF_SCAL + 1] = 0.f;
        ws[OFF_SCAL + 2] = 0.f;
    }
}

__global__ __launch_bounds__(256) void k_deg(const int* __restrict__ dst, int* __restrict__ deg) {
    int e = blockIdx.x * 256 + threadIdx.x;
    atomicAdd(&deg[dst[e]], 1);
}

// h = x @ W.  x:[N,128], W:[128,128]. 64x64 tile, 4x4 per thread.
__global__ __launch_bounds__(256) void k_gemm(const float* __restrict__ x,
                                              const float* __restrict__ W,
                                              float* __restrict__ h) {
    __shared__ float xs[64 * 132];
    __shared__ float wsm[128 * 64];
    int r0 = blockIdx.x * 64;
    int c0 = blockIdx.y * 64;
    int tid = threadIdx.x;

    #pragma unroll
    for (int i = 0; i < 8; i++) {
        int slot = tid + i * 256;
        int row = slot >> 5, k4 = slot & 31;
        float4 v = make_float4(0.f, 0.f, 0.f, 0.f);
        int gr = r0 + row;
        if (gr < N_NODES) v = *(const float4*)(x + gr * 128 + k4 * 4);
        *(float4*)(xs + row * 132 + k4 * 4) = v;
    }
    #pragma unroll
    for (int i = 0; i < 8; i++) {
        int slot = tid + i * 256;
        int k = slot >> 4, c4 = slot & 15;
        *(float4*)(wsm + k * 64 + c4 * 4) = *(const float4*)(W + k * 128 + c0 + c4 * 4);
    }
    __syncthreads();

    int tx = tid & 15, ty = tid >> 4;
    float acc[4][4];
    #pragma unroll
    for (int i = 0; i < 4; i++)
        #pragma unroll
        for (int j = 0; j < 4; j++) acc[i][j] = 0.f;

    for (int k = 0; k < 128; k++) {
        float4 wv = *(const float4*)(wsm + k * 64 + tx * 4);
        float xr[4];
        #pragma unroll
        for (int i = 0; i < 4; i++) xr[i] = xs[(ty * 4 + i) * 132 + k];
        #pragma unroll
        for (int i = 0; i < 4; i++) {
            acc[i][0] += xr[i] * wv.x;
            acc[i][1] += xr[i] * wv.y;
            acc[i][2] += xr[i] * wv.z;
            acc[i][3] += xr[i] * wv.w;
        }
    }
    #pragma unroll
    for (int i = 0; i < 4; i++) {
        int gr = r0 + ty * 4 + i;
        if (gr < N_NODES) {
            *(float4*)(h + gr * 128 + c0 + tx * 4) =
                make_float4(acc[i][0], acc[i][1], acc[i][2], acc[i][3]);
        }
    }
}

// ---- exclusive scan of deg -> rowstart (+dinv fused) ----
__global__ __launch_bounds__(256) void k_scan1(const int* __restrict__ deg,
                                               int* __restrict__ rowstart,
                                               int* __restrict__ blksum,
                                               float* __restrict__ dinv) {
    __shared__ int sh[256];
    int i = blockIdx.x * 256 + threadIdx.x;
    int v = (i < N_NODES) ? deg[i] : 0;
    if (i < N_NODES) dinv[i] = rsqrtf((float)(v + 1));  // +1 self-loop
    sh[threadIdx.x] = v;
    __syncthreads();
    #pragma unroll
    for (int off = 1; off < 256; off <<= 1) {
        int t = (threadIdx.x >= off) ? sh[threadIdx.x - off] : 0;
        __syncthreads();
        sh[threadIdx.x] += t;
        __syncthreads();
    }
    if (i < N_NODES) rowstart[i] = sh[threadIdx.x] - v;  // exclusive
    if (threadIdx.x == 255) blksum[blockIdx.x] = sh[255];
}

__global__ __launch_bounds__(256) void k_scan2(int* __restrict__ blksum, int nblk) {
    __shared__ int sh[256];
    int tid = threadIdx.x;
    int v = (tid < nblk) ? blksum[tid] : 0;
    sh[tid] = v;
    __syncthreads();
    #pragma unroll
    for (int off = 1; off < 256; off <<= 1) {
        int t = (tid >= off) ? sh[tid - off] : 0;
        __syncthreads();
        sh[tid] += t;
        __syncthreads();
    }
    if (tid < nblk) blksum[tid] = sh[tid] - v;  // exclusive
}

__global__ __launch_bounds__(256) void k_scan3(int* __restrict__ rowstart,
                                               const int* __restrict__ blksum,
                                               int* __restrict__ cursor) {
    int i = blockIdx.x * 256 + threadIdx.x;
    if (i < N_NODES) {
        rowstart[i] += blksum[blockIdx.x];
        cursor[i] = 0;
    }
    if (i == 0) rowstart[N_NODES] = N_EDGES;
}

__global__ __launch_bounds__(256) void k_bucket(const int* __restrict__ src,
                                                const int* __restrict__ dst,
                                                const int* __restrict__ rowstart,
                                                int* __restrict__ cursor,
                                                int* __restrict__ esrc) {
    int e = blockIdx.x * 256 + threadIdx.x;
    int d = dst[e];
    int pos = atomicAdd(&cursor[d], 1);
    esrc[rowstart[d] + pos] = src[e];
}

// Feature-chunked gather: chunk=16 floats -> per-chunk table 3.2MB, L2-resident per XCD.
// grid (3125, 8): blockIdx.y = chunk (slow dim: all resident blocks share one chunk).
// out[d][c] = b[c] + htmp[d][c]*dinv[d]^2 + sum_s htmp[s][c]*dinv[s]*dinv[d]
__global__ __launch_bounds__(256) void k_gather(const float* __restrict__ htmp,
                                                const float* __restrict__ dinv,
                                                const float* __restrict__ b,
                                                const int* __restrict__ rowstart,
                                                const int* __restrict__ esrc,
                                                float* __restrict__ out) {
    int node = blockIdx.x * 16 + (threadIdx.x >> 4);
    int c = blockIdx.y * 16 + (threadIdx.x & 15);
    float di = dinv[node];
    float acc = b[c] + htmp[node * 128 + c] * di * di;
    float acc2 = 0.f;
    int e0 = rowstart[node], e1 = rowstart[node + 1];
    int k = e0;
    for (; k + 1 < e1; k += 2) {  // 2 independent chains for MLP
        int s0 = esrc[k], s1 = esrc[k + 1];
        float n0 = dinv[s0], n1 = dinv[s1];
        acc  += htmp[s0 * 128 + c] * (di * n0);
        acc2 += htmp[s1 * 128 + c] * (di * n1);
    }
    if (k < e1) {
        int s0 = esrc[k];
        acc += htmp[s0 * 128 + c] * (di * dinv[s0]);
    }
    out[node * 128 + c] = acc + acc2;
}

// Chunked energy: E_part[chunk][node] = sum_s sum_{c in chunk} (out[s][c]-out[d][c])^2
__global__ __launch_bounds__(256) void k_energy(const float* __restrict__ out,
                                                const int* __restrict__ rowstart,
                                                const int* __restrict__ esrc,
                                                float* __restrict__ E_part) {
    int node = blockIdx.x * 16 + (threadIdx.x >> 4);
    int lane = threadIdx.x & 15;
    int c = blockIdx.y * 16 + lane;
    float od = out[node * 128 + c];
    float acc = 0.f, acc2 = 0.f;
    int e0 = rowstart[node], e1 = rowstart[node + 1];
    int k = e0;
    for (; k + 1 < e1; k += 2) {
        int s0 = esrc[k], s1 = esrc[k + 1];
        float d0 = out[s0 * 128 + c] - od;
        float d1 = out[s1 * 128 + c] - od;
        acc += d0 * d0; acc2 += d1 * d1;
    }
    if (k < e1) {
        int s0 = esrc[k];
        float d0 = out[s0 * 128 + c] - od;
        acc += d0 * d0;
    }
    acc += acc2;
    #pragma unroll
    for (int off = 8; off; off >>= 1) acc += __shfl_xor(acc, off);
    if (lane == 0) E_part[blockIdx.y * N_NODES + node] = acc;
}

__global__ __launch_bounds__(256) void k_ereduce(const float* __restrict__ E_part,
                                                 float* __restrict__ E) {
    int i = blockIdx.x * 256 + threadIdx.x;
    if (i < N_NODES) {
        float s = 0.f;
        #pragma unroll
        for (int ch = 0; ch < 8; ch++) s += E_part[ch * N_NODES + i];
        E[i] = s;
    }
}

__global__ __launch_bounds__(256) void k_emin(const float* __restrict__ E, int* __restrict__ scal) {
    __shared__ float sh[4];
    int i = blockIdx.x * 256 + threadIdx.x;
    float v = 3.402823466e38f;
    if (i < N_NODES) v = E[i];
    #pragma unroll
    for (int off = 32; off; off >>= 1) v = fminf(v, __shfl_xor(v, off));
    int lane = threadIdx.x & 63, wid = threadIdx.x >> 6;
    if (lane == 0) sh[wid] = v;
    __syncthreads();
    if (threadIdx.x == 0) {
        float m = fminf(fminf(sh[0], sh[1]), fminf(sh[2], sh[3]));
        atomicMin(scal, __float_as_int(m));  // valid: E >= 0
    }
}

__global__ __launch_bounds__(256) void k_sums(const float* __restrict__ E,
                                              const float* __restrict__ temp,
                                              const int* __restrict__ scal,
                                              float* __restrict__ S) {
    __shared__ float sh0[4], sh1[4];
    float Emin = __int_as_float(scal[0]);
    float T = temp[0];
    int i = blockIdx.x * 256 + threadIdx.x;
    float s0 = 0.f, s1 = 0.f;
    if (i < N_NODES) {
        float dd = (Emin - E[i]) / T;
        float ed = __expf(dd);
        s0 = ed; s1 = ed * dd;
    }
    #pragma unroll
    for (int off = 32; off; off >>= 1) { s0 += __shfl_xor(s0, off); s1 += __shfl_xor(s1, off); }
    int lane = threadIdx.x & 63, wid = threadIdx.x >> 6;
    if (lane == 0) { sh0[wid] = s0; sh1[wid] = s1; }
    __syncthreads();
    if (threadIdx.x == 0) {
        atomicAdd(&S[0], sh0[0] + sh0[1] + sh0[2] + sh0[3]);
        atomicAdd(&S[1], sh1[0] + sh1[1] + sh1[2] + sh1[3]);
    }
}

// q_i = (e^dd/S0)*(dd - S1/S0)/T,  dd=(Emin-E_i)/T
__global__ __launch_bounds__(256) void k_q(const float* __restrict__ E,
                                           const float* __restrict__ temp,
                                           const float* __restrict__ scal,
                                           float* __restrict__ q) {
    int i = blockIdx.x * 256 + threadIdx.x;
    if (i >= N_NODES) return;
    float Emin = __int_as_float(((const int*)scal)[0]);
    float S0 = scal[1], S1 = scal[2];
    float T = temp[0];
    float dd = (Emin - E[i]) / T;
    q[i] = (__expf(dd) / S0) * (dd - S1 / S0) / T;
}

// CSR-driven gradient: one 32-lane group per node; skip q==0 nodes (almost all).
// For active d: vec_s = 2*w*q[d]*(out_s - out_d); out[s] += vec_s; out[d] -= sum vec_s.
__global__ __launch_bounds__(256) void k_grad(const int* __restrict__ rowstart,
                                              const int* __restrict__ esrc,
                                              const float* __restrict__ q,
                                              const float* __restrict__ weight,
                                              float* __restrict__ out) {
    int node = blockIdx.x * 8 + (threadIdx.x >> 5);
    int lane = threadIdx.x & 31;
    float qd = q[node];
    if (qd == 0.f) return;
    float cc = 2.f * weight[0] * qd;
    float4 od = *(const float4*)(out + node * 128 + lane * 4);
    float sx = 0.f, sy = 0.f, sz = 0.f, sw = 0.f;
    int e0 = rowstart[node], e1 = rowstart[node + 1];
    for (int k = e0; k < e1; k++) {
        int s = esrc[k];
        float4 a = *(const float4*)(out + s * 128 + lane * 4);
        float vx = cc * (a.x - od.x), vy = cc * (a.y - od.y);
        float vz = cc * (a.z - od.z), vw = cc * (a.w - od.w);
        float* os = out + s * 128 + lane * 4;
        atomicAdd(os + 0, vx); atomicAdd(os + 1, vy);
        atomicAdd(os + 2, vz); atomicAdd(os + 3, vw);
        sx += vx; sy += vy; sz += vz; sw += vw;
    }
    float* odp = out + node * 128 + lane * 4;
    atomicAdd(odp + 0, -sx); atomicAdd(odp + 1, -sy);
    atomicAdd(odp + 2, -sz); atomicAdd(odp + 3, -sw);
}

extern "C" void kernel_launch(void* const* d_in, const int* in_sizes, int n_in,
                              void* d_out, int out_size, void* d_ws, size_t ws_size,
                              hipStream_t stream) {
    const float* x      = (const float*)d_in[0];
    const int*   ei     = (const int*)d_in[1];
    const float* weight = (const float*)d_in[2];
    const float* temp   = (const float*)d_in[3];
    const float* W      = (const float*)d_in[4];
    const float* b      = (const float*)d_in[5];
    float* out = (float*)d_out;
    float* ws  = (float*)d_ws;

    const int* src = ei;
    const int* dst = ei + N_EDGES;

    float* htmp     = ws + OFF_HTMP;
    int*   deg      = (int*)(ws + OFF_DEG);
    int*   rowstart = (int*)(ws + OFF_ROWSTART);
    int*   cursor   = (int*)(ws + OFF_CURSOR);
    float* dinv     = ws + OFF_DINV;
    float* Earr     = ws + OFF_E;
    float* qarr     = ws + OFF_Q;
    float* scal     = ws + OFF_SCAL;
    int*   blksum   = (int*)(ws + OFF_BLKSUM);
    int*   esrc     = (int*)(ws + OFF_ESRC);
    float* epart    = ws + OFF_EPART;

    const int NBLK = 196;  // ceil(50000/256)

    k_init<<<NBLK, 256, 0, stream>>>(ws);
    k_deg<<<N_EDGES / 256, 256, 0, stream>>>(dst, deg);
    k_gemm<<<dim3(782, 2), 256, 0, stream>>>(x, W, htmp);
    k_scan1<<<NBLK, 256, 0, stream>>>(deg, rowstart, blksum, dinv);
    k_scan2<<<1, 256, 0, stream>>>(blksum, NBLK);
    k_scan3<<<NBLK, 256, 0, stream>>>(rowstart, blksum, cursor);
    k_bucket<<<N_EDGES / 256, 256, 0, stream>>>(src, dst, rowstart, cursor, esrc);
    k_gather<<<dim3(3125, 8), 256, 0, stream>>>(htmp, dinv, b, rowstart, esrc, out);
    k_energy<<<dim3(3125, 8), 256, 0, stream>>>(out, rowstart, esrc, epart);
    k_ereduce<<<NBLK, 256, 0, stream>>>(epart, Earr);
    k_emin<<<NBLK, 256, 0, stream>>>(Earr, (int*)scal);
    k_sums<<<NBLK, 256, 0, stream>>>(Earr, temp, (const int*)scal, scal + 1);
    k_q<<<NBLK, 256, 0, stream>>>(Earr, temp, scal, qarr);
    k_grad<<<6250, 256, 0, stream>>>(rowstart, esrc, qarr, weight, out);
}

// Round 4
// 304.561 us; speedup vs baseline: 1.4387x; 1.4387x over previous
//
#include <hip/hip_runtime.h>

#define N_NODES 50000
#define N_EDGES 640000

// workspace layout (float/int offsets, 4B units)
#define OFF_HTMP     0          // float[6400000]
#define OFF_DEG      6400000    // int[50000]
#define OFF_ROWSTART 6450000    // int[50001]
#define OFF_CURSOR   6500016    // int[50000]
#define OFF_DINV     6550016    // float[50000]
#define OFF_E        6600016    // float[50000]
#define OFF_SCAL     6650016    // [0]=EminBits [1]=S0 [2]=S1
#define OFF_BLKSUM   6650020    // int[256]
#define OFF_ESRC     6650276    // int[640000] CSR-bucketed source ids

__global__ __launch_bounds__(256) void k_init(float* ws) {
    int i = blockIdx.x * 256 + threadIdx.x;
    if (i < N_NODES) ((int*)(ws + OFF_DEG))[i] = 0;
    if (i == 0) {
        ((int*)(ws + OFF_SCAL))[0] = 0x7F7FFFFF;  // FLT_MAX bits
        ws[OFF_SCAL + 1] = 0.f;
        ws[OFF_SCAL + 2] = 0.f;
    }
}

__global__ __launch_bounds__(256) void k_deg(const int* __restrict__ dst, int* __restrict__ deg) {
    int e = blockIdx.x * 256 + threadIdx.x;
    atomicAdd(&deg[dst[e]], 1);
}

// h = x @ W.  x:[N,128], W:[128,128]. 64x64 tile, 4x4 per thread.
__global__ __launch_bounds__(256) void k_gemm(const float* __restrict__ x,
                                              const float* __restrict__ W,
                                              float* __restrict__ h) {
    __shared__ float xs[64 * 132];
    __shared__ float wsm[128 * 64];
    int r0 = blockIdx.x * 64;
    int c0 = blockIdx.y * 64;
    int tid = threadIdx.x;

    #pragma unroll
    for (int i = 0; i < 8; i++) {
        int slot = tid + i * 256;
        int row = slot >> 5, k4 = slot & 31;
        float4 v = make_float4(0.f, 0.f, 0.f, 0.f);
        int gr = r0 + row;
        if (gr < N_NODES) v = *(const float4*)(x + gr * 128 + k4 * 4);
        *(float4*)(xs + row * 132 + k4 * 4) = v;
    }
    #pragma unroll
    for (int i = 0; i < 8; i++) {
        int slot = tid + i * 256;
        int k = slot >> 4, c4 = slot & 15;
        *(float4*)(wsm + k * 64 + c4 * 4) = *(const float4*)(W + k * 128 + c0 + c4 * 4);
    }
    __syncthreads();

    int tx = tid & 15, ty = tid >> 4;
    float acc[4][4];
    #pragma unroll
    for (int i = 0; i < 4; i++)
        #pragma unroll
        for (int j = 0; j < 4; j++) acc[i][j] = 0.f;

    for (int k = 0; k < 128; k++) {
        float4 wv = *(const float4*)(wsm + k * 64 + tx * 4);
        float xr[4];
        #pragma unroll
        for (int i = 0; i < 4; i++) xr[i] = xs[(ty * 4 + i) * 132 + k];
        #pragma unroll
        for (int i = 0; i < 4; i++) {
            acc[i][0] += xr[i] * wv.x;
            acc[i][1] += xr[i] * wv.y;
            acc[i][2] += xr[i] * wv.z;
            acc[i][3] += xr[i] * wv.w;
        }
    }
    #pragma unroll
    for (int i = 0; i < 4; i++) {
        int gr = r0 + ty * 4 + i;
        if (gr < N_NODES) {
            *(float4*)(h + gr * 128 + c0 + tx * 4) =
                make_float4(acc[i][0], acc[i][1], acc[i][2], acc[i][3]);
        }
    }
}

// ---- exclusive scan of deg -> rowstart (+dinv fused) ----
__global__ __launch_bounds__(256) void k_scan1(const int* __restrict__ deg,
                                               int* __restrict__ rowstart,
                                               int* __restrict__ blksum,
                                               float* __restrict__ dinv) {
    __shared__ int sh[256];
    int i = blockIdx.x * 256 + threadIdx.x;
    int v = (i < N_NODES) ? deg[i] : 0;
    if (i < N_NODES) dinv[i] = rsqrtf((float)(v + 1));  // +1 self-loop
    sh[threadIdx.x] = v;
    __syncthreads();
    #pragma unroll
    for (int off = 1; off < 256; off <<= 1) {
        int t = (threadIdx.x >= off) ? sh[threadIdx.x - off] : 0;
        __syncthreads();
        sh[threadIdx.x] += t;
        __syncthreads();
    }
    if (i < N_NODES) rowstart[i] = sh[threadIdx.x] - v;  // exclusive
    if (threadIdx.x == 255) blksum[blockIdx.x] = sh[255];
}

__global__ __launch_bounds__(256) void k_scan2(int* __restrict__ blksum, int nblk) {
    __shared__ int sh[256];
    int tid = threadIdx.x;
    int v = (tid < nblk) ? blksum[tid] : 0;
    sh[tid] = v;
    __syncthreads();
    #pragma unroll
    for (int off = 1; off < 256; off <<= 1) {
        int t = (tid >= off) ? sh[tid - off] : 0;
        __syncthreads();
        sh[tid] += t;
        __syncthreads();
    }
    if (tid < nblk) blksum[tid] = sh[tid] - v;  // exclusive
}

__global__ __launch_bounds__(256) void k_scan3(int* __restrict__ rowstart,
                                               const int* __restrict__ blksum,
                                               int* __restrict__ cursor) {
    int i = blockIdx.x * 256 + threadIdx.x;
    if (i < N_NODES) {
        rowstart[i] += blksum[blockIdx.x];
        cursor[i] = 0;
    }
    if (i == 0) rowstart[N_NODES] = N_EDGES;
}

__global__ __launch_bounds__(256) void k_bucket(const int* __restrict__ src,
                                                const int* __restrict__ dst,
                                                const int* __restrict__ rowstart,
                                                int* __restrict__ cursor,
                                                int* __restrict__ esrc) {
    int e = blockIdx.x * 256 + threadIdx.x;
    int d = dst[e];
    int pos = atomicAdd(&cursor[d], 1);
    esrc[rowstart[d] + pos] = src[e];
}

// per node (32 lanes, float4/lane), 2-way edge unroll (2 independent load chains):
// out[d] = b + htmp[d]*dinv[d]^2 + sum_s htmp[s]*dinv[s]*dinv[d]
__global__ __launch_bounds__(256) void k_gather(const float* __restrict__ htmp,
                                                const float* __restrict__ dinv,
                                                const float* __restrict__ b,
                                                const int* __restrict__ rowstart,
                                                const int* __restrict__ esrc,
                                                float* __restrict__ out) {
    int node = blockIdx.x * 8 + (threadIdx.x >> 5);
    int lane = threadIdx.x & 31;
    float di = dinv[node];
    float4 bv = *(const float4*)(b + lane * 4);
    float4 hv = *(const float4*)(htmp + node * 128 + lane * 4);
    float sl = di * di;
    float ax = bv.x + hv.x * sl, ay = bv.y + hv.y * sl;
    float az = bv.z + hv.z * sl, aw = bv.w + hv.w * sl;
    float cx = 0.f, cy = 0.f, cz = 0.f, cw = 0.f;
    int e0 = rowstart[node], e1 = rowstart[node + 1];
    int k = e0;
    for (; k + 1 < e1; k += 2) {
        int s0 = esrc[k], s1 = esrc[k + 1];
        float n0 = di * dinv[s0], n1 = di * dinv[s1];
        float4 v0 = *(const float4*)(htmp + s0 * 128 + lane * 4);
        float4 v1 = *(const float4*)(htmp + s1 * 128 + lane * 4);
        ax += v0.x * n0; ay += v0.y * n0; az += v0.z * n0; aw += v0.w * n0;
        cx += v1.x * n1; cy += v1.y * n1; cz += v1.z * n1; cw += v1.w * n1;
    }
    if (k < e1) {
        int s0 = esrc[k];
        float n0 = di * dinv[s0];
        float4 v0 = *(const float4*)(htmp + s0 * 128 + lane * 4);
        ax += v0.x * n0; ay += v0.y * n0; az += v0.z * n0; aw += v0.w * n0;
    }
    *(float4*)(out + node * 128 + lane * 4) =
        make_float4(ax + cx, ay + cy, az + cz, aw + cw);
}

// per node: E[d] = sum_{edges into d} ||out[s]-out[d]||^2 (gather, 2 chains, no atomics)
__global__ __launch_bounds__(256) void k_energy(const float* __restrict__ out,
                                                const int* __restrict__ rowstart,
                                                const int* __restrict__ esrc,
                                                float* __restrict__ E) {
    int node = blockIdx.x * 8 + (threadIdx.x >> 5);
    int lane = threadIdx.x & 31;
    float4 od = *(const float4*)(out + node * 128 + lane * 4);
    float acc = 0.f, acc2 = 0.f;
    int e0 = rowstart[node], e1 = rowstart[node + 1];
    int k = e0;
    for (; k + 1 < e1; k += 2) {
        int s0 = esrc[k], s1 = esrc[k + 1];
        float4 a = *(const float4*)(out + s0 * 128 + lane * 4);
        float4 c = *(const float4*)(out + s1 * 128 + lane * 4);
        float dx = a.x - od.x, dy = a.y - od.y, dz = a.z - od.z, dw = a.w - od.w;
        float ex = c.x - od.x, ey = c.y - od.y, ez = c.z - od.z, ew = c.w - od.w;
        acc  += dx * dx + dy * dy + dz * dz + dw * dw;
        acc2 += ex * ex + ey * ey + ez * ez + ew * ew;
    }
    if (k < e1) {
        int s0 = esrc[k];
        float4 a = *(const float4*)(out + s0 * 128 + lane * 4);
        float dx = a.x - od.x, dy = a.y - od.y, dz = a.z - od.z, dw = a.w - od.w;
        acc += dx * dx + dy * dy + dz * dz + dw * dw;
    }
    acc += acc2;
    #pragma unroll
    for (int off = 16; off; off >>= 1) acc += __shfl_xor(acc, off);
    if (lane == 0) E[node] = acc;
}

__global__ __launch_bounds__(256) void k_emin(const float* __restrict__ E, int* __restrict__ scal) {
    __shared__ float sh[4];
    int i = blockIdx.x * 256 + threadIdx.x;
    float v = 3.402823466e38f;
    if (i < N_NODES) v = E[i];
    #pragma unroll
    for (int off = 32; off; off >>= 1) v = fminf(v, __shfl_xor(v, off));
    int lane = threadIdx.x & 63, wid = threadIdx.x >> 6;
    if (lane == 0) sh[wid] = v;
    __syncthreads();
    if (threadIdx.x == 0) {
        float m = fminf(fminf(sh[0], sh[1]), fminf(sh[2], sh[3]));
        atomicMin(scal, __float_as_int(m));  // valid: E >= 0
    }
}

__global__ __launch_bounds__(256) void k_sums(const float* __restrict__ E,
                                              const float* __restrict__ temp,
                                              const int* __restrict__ scal,
                                              float* __restrict__ S) {
    __shared__ float sh0[4], sh1[4];
    float Emin = __int_as_float(scal[0]);
    float T = temp[0];
    int i = blockIdx.x * 256 + threadIdx.x;
    float s0 = 0.f, s1 = 0.f;
    if (i < N_NODES) {
        float dd = (Emin - E[i]) / T;
        float ed = __expf(dd);
        s0 = ed; s1 = ed * dd;
    }
    #pragma unroll
    for (int off = 32; off; off >>= 1) { s0 += __shfl_xor(s0, off); s1 += __shfl_xor(s1, off); }
    int lane = threadIdx.x & 63, wid = threadIdx.x >> 6;
    if (lane == 0) { sh0[wid] = s0; sh1[wid] = s1; }
    __syncthreads();
    if (threadIdx.x == 0) {
        atomicAdd(&S[0], sh0[0] + sh0[1] + sh0[2] + sh0[3]);
        atomicAdd(&S[1], sh1[0] + sh1[1] + sh1[2] + sh1[3]);
    }
}

// CSR-driven gradient with inline q: one 32-lane group per node; skip q==0 (almost all).
// q_d = (e^dd/S0)*(dd - S1/S0)/T, dd=(Emin-E_d)/T.
// For active d: vec_s = 2*w*q_d*(out_s - out_d); out[s] += vec_s; out[d] -= sum vec_s.
__global__ __launch_bounds__(256) void k_grad(const int* __restrict__ rowstart,
                                              const int* __restrict__ esrc,
                                              const float* __restrict__ E,
                                              const float* __restrict__ temp,
                                              const float* __restrict__ scal,
                                              const float* __restrict__ weight,
                                              float* __restrict__ out) {
    int node = blockIdx.x * 8 + (threadIdx.x >> 5);
    int lane = threadIdx.x & 31;
    float Emin = __int_as_float(((const int*)scal)[0]);
    float S0 = scal[1], S1 = scal[2];
    float T = temp[0];
    float dd = (Emin - E[node]) / T;
    float qd = (__expf(dd) / S0) * (dd - S1 / S0) / T;
    if (qd == 0.f) return;
    float cc = 2.f * weight[0] * qd;
    float4 od = *(const float4*)(out + node * 128 + lane * 4);
    float sx = 0.f, sy = 0.f, sz = 0.f, sw = 0.f;
    int e0 = rowstart[node], e1 = rowstart[node + 1];
    for (int k = e0; k < e1; k++) {
        int s = esrc[k];
        float4 a = *(const float4*)(out + s * 128 + lane * 4);
        float vx = cc * (a.x - od.x), vy = cc * (a.y - od.y);
        float vz = cc * (a.z - od.z), vw = cc * (a.w - od.w);
        float* os = out + s * 128 + lane * 4;
        atomicAdd(os + 0, vx); atomicAdd(os + 1, vy);
        atomicAdd(os + 2, vz); atomicAdd(os + 3, vw);
        sx += vx; sy += vy; sz += vz; sw += vw;
    }
    float* odp = out + node * 128 + lane * 4;
    atomicAdd(odp + 0, -sx); atomicAdd(odp + 1, -sy);
    atomicAdd(odp + 2, -sz); atomicAdd(odp + 3, -sw);
}

extern "C" void kernel_launch(void* const* d_in, const int* in_sizes, int n_in,
                              void* d_out, int out_size, void* d_ws, size_t ws_size,
                              hipStream_t stream) {
    const float* x      = (const float*)d_in[0];
    const int*   ei     = (const int*)d_in[1];
    const float* weight = (const float*)d_in[2];
    const float* temp   = (const float*)d_in[3];
    const float* W      = (const float*)d_in[4];
    const float* b      = (const float*)d_in[5];
    float* out = (float*)d_out;
    float* ws  = (float*)d_ws;

    const int* src = ei;
    const int* dst = ei + N_EDGES;

    float* htmp     = ws + OFF_HTMP;
    int*   deg      = (int*)(ws + OFF_DEG);
    int*   rowstart = (int*)(ws + OFF_ROWSTART);
    int*   cursor   = (int*)(ws + OFF_CURSOR);
    float* dinv     = ws + OFF_DINV;
    float* Earr     = ws + OFF_E;
    float* scal     = ws + OFF_SCAL;
    int*   blksum   = (int*)(ws + OFF_BLKSUM);
    int*   esrc     = (int*)(ws + OFF_ESRC);

    const int NBLK = 196;  // ceil(50000/256)

    k_init<<<NBLK, 256, 0, stream>>>(ws);
    k_deg<<<N_EDGES / 256, 256, 0, stream>>>(dst, deg);
    k_gemm<<<dim3(782, 2), 256, 0, stream>>>(x, W, htmp);
    k_scan1<<<NBLK, 256, 0, stream>>>(deg, rowstart, blksum, dinv);
    k_scan2<<<1, 256, 0, stream>>>(blksum, NBLK);
    k_scan3<<<NBLK, 256, 0, stream>>>(rowstart, blksum, cursor);
    k_bucket<<<N_EDGES / 256, 256, 0, stream>>>(src, dst, rowstart, cursor, esrc);
    k_gather<<<6250, 256, 0, stream>>>(htmp, dinv, b, rowstart, esrc, out);
    k_energy<<<6250, 256, 0, stream>>>(out, rowstart, esrc, Earr);
    k_emin<<<NBLK, 256, 0, stream>>>(Earr, (int*)scal);
    k_sums<<<NBLK, 256, 0, stream>>>(Earr, temp, (const int*)scal, scal + 1);
    k_grad<<<6250, 256, 0, stream>>>(rowstart, esrc, Earr, temp, scal, weight, out);
}

// Round 5
// 286.395 us; speedup vs baseline: 1.5300x; 1.0634x over previous
//
#include <hip/hip_runtime.h>

#define N_NODES 50000
#define N_EDGES 640000

// workspace layout (4B units)
#define OFF_HTMPB    0          // ushort[6400000] bf16 h=xW  -> 3200000 floats
#define OFF_OBF      3200000    // ushort[6400000] bf16 copy of out
#define OFF_DEG      6400000    // int[50000]
#define OFF_ROWSTART 6450000    // int[50001]
#define OFF_CURSOR   6500016    // int[50000]
#define OFF_DINV     6550016    // float[50000]
#define OFF_E        6600016    // float[50000]
#define OFF_SCAL     6650016    // [0]=EminBits [1]=S0 [2]=S1
#define OFF_BLKSUM   6650020    // int[256]
#define OFF_ESRC     6650276    // int[640000] CSR-bucketed source ids

__device__ __forceinline__ unsigned short f2bf(float f) {  // RNE
    unsigned u = __float_as_uint(f);
    unsigned r = u + 0x7fffu + ((u >> 16) & 1u);
    return (unsigned short)(r >> 16);
}
__device__ __forceinline__ float bflo(unsigned u) { return __uint_as_float(u << 16); }
__device__ __forceinline__ float bfhi(unsigned u) { return __uint_as_float(u & 0xffff0000u); }

__global__ __launch_bounds__(256) void k_init(float* ws) {
    int i = blockIdx.x * 256 + threadIdx.x;
    if (i < N_NODES) ((int*)(ws + OFF_DEG))[i] = 0;
    if (i == 0) {
        ((int*)(ws + OFF_SCAL))[0] = 0x7F7FFFFF;  // FLT_MAX bits
        ws[OFF_SCAL + 1] = 0.f;
        ws[OFF_SCAL + 2] = 0.f;
    }
}

__global__ __launch_bounds__(256) void k_deg(const int* __restrict__ dst, int* __restrict__ deg) {
    int e = blockIdx.x * 256 + threadIdx.x;
    atomicAdd(&deg[dst[e]], 1);
}

// h = x @ W (f32 compute), store bf16. 64x64 tile, 4x4 per thread.
__global__ __launch_bounds__(256) void k_gemm(const float* __restrict__ x,
                                              const float* __restrict__ W,
                                              unsigned short* __restrict__ htmpb) {
    __shared__ float xs[64 * 132];
    __shared__ float wsm[128 * 64];
    int r0 = blockIdx.x * 64;
    int c0 = blockIdx.y * 64;
    int tid = threadIdx.x;

    #pragma unroll
    for (int i = 0; i < 8; i++) {
        int slot = tid + i * 256;
        int row = slot >> 5, k4 = slot & 31;
        float4 v = make_float4(0.f, 0.f, 0.f, 0.f);
        int gr = r0 + row;
        if (gr < N_NODES) v = *(const float4*)(x + gr * 128 + k4 * 4);
        *(float4*)(xs + row * 132 + k4 * 4) = v;
    }
    #pragma unroll
    for (int i = 0; i < 8; i++) {
        int slot = tid + i * 256;
        int k = slot >> 4, c4 = slot & 15;
        *(float4*)(wsm + k * 64 + c4 * 4) = *(const float4*)(W + k * 128 + c0 + c4 * 4);
    }
    __syncthreads();

    int tx = tid & 15, ty = tid >> 4;
    float acc[4][4];
    #pragma unroll
    for (int i = 0; i < 4; i++)
        #pragma unroll
        for (int j = 0; j < 4; j++) acc[i][j] = 0.f;

    for (int k = 0; k < 128; k++) {
        float4 wv = *(const float4*)(wsm + k * 64 + tx * 4);
        float xr[4];
        #pragma unroll
        for (int i = 0; i < 4; i++) xr[i] = xs[(ty * 4 + i) * 132 + k];
        #pragma unroll
        for (int i = 0; i < 4; i++) {
            acc[i][0] += xr[i] * wv.x;
            acc[i][1] += xr[i] * wv.y;
            acc[i][2] += xr[i] * wv.z;
            acc[i][3] += xr[i] * wv.w;
        }
    }
    #pragma unroll
    for (int i = 0; i < 4; i++) {
        int gr = r0 + ty * 4 + i;
        if (gr < N_NODES) {
            unsigned p0 = (unsigned)f2bf(acc[i][0]) | ((unsigned)f2bf(acc[i][1]) << 16);
            unsigned p1 = (unsigned)f2bf(acc[i][2]) | ((unsigned)f2bf(acc[i][3]) << 16);
            uint2 pk; pk.x = p0; pk.y = p1;
            *(uint2*)(htmpb + gr * 128 + c0 + tx * 4) = pk;
        }
    }
}

// ---- exclusive scan of deg -> rowstart (+dinv fused) ----
__global__ __launch_bounds__(256) void k_scan1(const int* __restrict__ deg,
                                               int* __restrict__ rowstart,
                                               int* __restrict__ blksum,
                                               float* __restrict__ dinv) {
    __shared__ int sh[256];
    int i = blockIdx.x * 256 + threadIdx.x;
    int v = (i < N_NODES) ? deg[i] : 0;
    if (i < N_NODES) dinv[i] = rsqrtf((float)(v + 1));  // +1 self-loop
    sh[threadIdx.x] = v;
    __syncthreads();
    #pragma unroll
    for (int off = 1; off < 256; off <<= 1) {
        int t = (threadIdx.x >= off) ? sh[threadIdx.x - off] : 0;
        __syncthreads();
        sh[threadIdx.x] += t;
        __syncthreads();
    }
    if (i < N_NODES) rowstart[i] = sh[threadIdx.x] - v;  // exclusive
    if (threadIdx.x == 255) blksum[blockIdx.x] = sh[255];
}

__global__ __launch_bounds__(256) void k_scan2(int* __restrict__ blksum, int nblk) {
    __shared__ int sh[256];
    int tid = threadIdx.x;
    int v = (tid < nblk) ? blksum[tid] : 0;
    sh[tid] = v;
    __syncthreads();
    #pragma unroll
    for (int off = 1; off < 256; off <<= 1) {
        int t = (tid >= off) ? sh[tid - off] : 0;
        __syncthreads();
        sh[tid] += t;
        __syncthreads();
    }
    if (tid < nblk) blksum[tid] = sh[tid] - v;  // exclusive
}

__global__ __launch_bounds__(256) void k_scan3(int* __restrict__ rowstart,
                                               const int* __restrict__ blksum,
                                               int* __restrict__ cursor) {
    int i = blockIdx.x * 256 + threadIdx.x;
    if (i < N_NODES) {
        rowstart[i] += blksum[blockIdx.x];
        cursor[i] = 0;
    }
    if (i == 0) rowstart[N_NODES] = N_EDGES;
}

__global__ __launch_bounds__(256) void k_bucket(const int* __restrict__ src,
                                                const int* __restrict__ dst,
                                                const int* __restrict__ rowstart,
                                                int* __restrict__ cursor,
                                                int* __restrict__ esrc) {
    int e = blockIdx.x * 256 + threadIdx.x;
    int d = dst[e];
    int pos = atomicAdd(&cursor[d], 1);
    esrc[rowstart[d] + pos] = src[e];
}

// per node (32 lanes, 4 bf16 per lane via uint2), 2 chains:
// out[d] = b + htmp[d]*dinv[d]^2 + sum_s htmp[s]*dinv[s]*dinv[d]; also bf16 copy obf.
__global__ __launch_bounds__(256) void k_gather(const unsigned short* __restrict__ htmpb,
                                                const float* __restrict__ dinv,
                                                const float* __restrict__ b,
                                                const int* __restrict__ rowstart,
                                                const int* __restrict__ esrc,
                                                float* __restrict__ out,
                                                unsigned short* __restrict__ obf) {
    int node = blockIdx.x * 8 + (threadIdx.x >> 5);
    int lane = threadIdx.x & 31;
    float di = dinv[node];
    float4 bv = *(const float4*)(b + lane * 4);
    uint2 hv = *(const uint2*)(htmpb + node * 128 + lane * 4);
    float sl = di * di;
    float ax = bv.x + bflo(hv.x) * sl, ay = bv.y + bfhi(hv.x) * sl;
    float az = bv.z + bflo(hv.y) * sl, aw = bv.w + bfhi(hv.y) * sl;
    float cx = 0.f, cy = 0.f, cz = 0.f, cw = 0.f;
    int e0 = rowstart[node], e1 = rowstart[node + 1];
    int k = e0;
    for (; k + 1 < e1; k += 2) {
        int s0 = esrc[k], s1 = esrc[k + 1];
        float n0 = di * dinv[s0], n1 = di * dinv[s1];
        uint2 u0 = *(const uint2*)(htmpb + s0 * 128 + lane * 4);
        uint2 u1 = *(const uint2*)(htmpb + s1 * 128 + lane * 4);
        ax += bflo(u0.x) * n0; ay += bfhi(u0.x) * n0;
        az += bflo(u0.y) * n0; aw += bfhi(u0.y) * n0;
        cx += bflo(u1.x) * n1; cy += bfhi(u1.x) * n1;
        cz += bflo(u1.y) * n1; cw += bfhi(u1.y) * n1;
    }
    if (k < e1) {
        int s0 = esrc[k];
        float n0 = di * dinv[s0];
        uint2 u0 = *(const uint2*)(htmpb + s0 * 128 + lane * 4);
        ax += bflo(u0.x) * n0; ay += bfhi(u0.x) * n0;
        az += bflo(u0.y) * n0; aw += bfhi(u0.y) * n0;
    }
    ax += cx; ay += cy; az += cz; aw += cw;
    *(float4*)(out + node * 128 + lane * 4) = make_float4(ax, ay, az, aw);
    uint2 pk;
    pk.x = (unsigned)f2bf(ax) | ((unsigned)f2bf(ay) << 16);
    pk.y = (unsigned)f2bf(az) | ((unsigned)f2bf(aw) << 16);
    *(uint2*)(obf + node * 128 + lane * 4) = pk;
}

// per node: E[d] = sum_{edges into d} ||out[s]-out[d]||^2 from bf16 copy, 2 chains.
__global__ __launch_bounds__(256) void k_energy(const unsigned short* __restrict__ obf,
                                                const int* __restrict__ rowstart,
                                                const int* __restrict__ esrc,
                                                float* __restrict__ E) {
    int node = blockIdx.x * 8 + (threadIdx.x >> 5);
    int lane = threadIdx.x & 31;
    uint2 ud = *(const uint2*)(obf + node * 128 + lane * 4);
    float o0 = bflo(ud.x), o1 = bfhi(ud.x), o2 = bflo(ud.y), o3 = bfhi(ud.y);
    float acc = 0.f, acc2 = 0.f;
    int e0 = rowstart[node], e1 = rowstart[node + 1];
    int k = e0;
    for (; k + 1 < e1; k += 2) {
        int s0 = esrc[k], s1 = esrc[k + 1];
        uint2 a = *(const uint2*)(obf + s0 * 128 + lane * 4);
        uint2 c = *(const uint2*)(obf + s1 * 128 + lane * 4);
        float d0 = bflo(a.x) - o0, d1 = bfhi(a.x) - o1;
        float d2 = bflo(a.y) - o2, d3 = bfhi(a.y) - o3;
        float e4 = bflo(c.x) - o0, e5 = bfhi(c.x) - o1;
        float e6 = bflo(c.y) - o2, e7 = bfhi(c.y) - o3;
        acc  += d0 * d0 + d1 * d1 + d2 * d2 + d3 * d3;
        acc2 += e4 * e4 + e5 * e5 + e6 * e6 + e7 * e7;
    }
    if (k < e1) {
        int s0 = esrc[k];
        uint2 a = *(const uint2*)(obf + s0 * 128 + lane * 4);
        float d0 = bflo(a.x) - o0, d1 = bfhi(a.x) - o1;
        float d2 = bflo(a.y) - o2, d3 = bfhi(a.y) - o3;
        acc += d0 * d0 + d1 * d1 + d2 * d2 + d3 * d3;
    }
    acc += acc2;
    #pragma unroll
    for (int off = 16; off; off >>= 1) acc += __shfl_xor(acc, off);
    if (lane == 0) E[node] = acc;
}

__global__ __launch_bounds__(256) void k_emin(const float* __restrict__ E, int* __restrict__ scal) {
    __shared__ float sh[4];
    int i = blockIdx.x * 256 + threadIdx.x;
    float v = 3.402823466e38f;
    if (i < N_NODES) v = E[i];
    #pragma unroll
    for (int off = 32; off; off >>= 1) v = fminf(v, __shfl_xor(v, off));
    int lane = threadIdx.x & 63, wid = threadIdx.x >> 6;
    if (lane == 0) sh[wid] = v;
    __syncthreads();
    if (threadIdx.x == 0) {
        float m = fminf(fminf(sh[0], sh[1]), fminf(sh[2], sh[3]));
        atomicMin(scal, __float_as_int(m));  // valid: E >= 0
    }
}

__global__ __launch_bounds__(256) void k_sums(const float* __restrict__ E,
                                              const float* __restrict__ temp,
                                              const int* __restrict__ scal,
                                              float* __restrict__ S) {
    __shared__ float sh0[4], sh1[4];
    float Emin = __int_as_float(scal[0]);
    float T = temp[0];
    int i = blockIdx.x * 256 + threadIdx.x;
    float s0 = 0.f, s1 = 0.f;
    if (i < N_NODES) {
        float dd = (Emin - E[i]) / T;
        float ed = __expf(dd);
        s0 = ed; s1 = ed * dd;
    }
    #pragma unroll
    for (int off = 32; off; off >>= 1) { s0 += __shfl_xor(s0, off); s1 += __shfl_xor(s1, off); }
    int lane = threadIdx.x & 63, wid = threadIdx.x >> 6;
    if (lane == 0) { sh0[wid] = s0; sh1[wid] = s1; }
    __syncthreads();
    if (threadIdx.x == 0) {
        atomicAdd(&S[0], sh0[0] + sh0[1] + sh0[2] + sh0[3]);
        atomicAdd(&S[1], sh1[0] + sh1[1] + sh1[2] + sh1[3]);
    }
}

// CSR-driven gradient with inline q (f32 out path): skip q==0 nodes (almost all).
__global__ __launch_bounds__(256) void k_grad(const int* __restrict__ rowstart,
                                              const int* __restrict__ esrc,
                                              const float* __restrict__ E,
                                              const float* __restrict__ temp,
                                              const float* __restrict__ scal,
                                              const float* __restrict__ weight,
                                              float* __restrict__ out) {
    int node = blockIdx.x * 8 + (threadIdx.x >> 5);
    int lane = threadIdx.x & 31;
    float Emin = __int_as_float(((const int*)scal)[0]);
    float S0 = scal[1], S1 = scal[2];
    float T = temp[0];
    float dd = (Emin - E[node]) / T;
    float qd = (__expf(dd) / S0) * (dd - S1 / S0) / T;
    if (qd == 0.f) return;
    float cc = 2.f * weight[0] * qd;
    float4 od = *(const float4*)(out + node * 128 + lane * 4);
    float sx = 0.f, sy = 0.f, sz = 0.f, sw = 0.f;
    int e0 = rowstart[node], e1 = rowstart[node + 1];
    for (int k = e0; k < e1; k++) {
        int s = esrc[k];
        float4 a = *(const float4*)(out + s * 128 + lane * 4);
        float vx = cc * (a.x - od.x), vy = cc * (a.y - od.y);
        float vz = cc * (a.z - od.z), vw = cc * (a.w - od.w);
        float* os = out + s * 128 + lane * 4;
        atomicAdd(os + 0, vx); atomicAdd(os + 1, vy);
        atomicAdd(os + 2, vz); atomicAdd(os + 3, vw);
        sx += vx; sy += vy; sz += vz; sw += vw;
    }
    float* odp = out + node * 128 + lane * 4;
    atomicAdd(odp + 0, -sx); atomicAdd(odp + 1, -sy);
    atomicAdd(odp + 2, -sz); atomicAdd(odp + 3, -sw);
}

extern "C" void kernel_launch(void* const* d_in, const int* in_sizes, int n_in,
                              void* d_out, int out_size, void* d_ws, size_t ws_size,
                              hipStream_t stream) {
    const float* x      = (const float*)d_in[0];
    const int*   ei     = (const int*)d_in[1];
    const float* weight = (const float*)d_in[2];
    const float* temp   = (const float*)d_in[3];
    const float* W      = (const float*)d_in[4];
    const float* b      = (const float*)d_in[5];
    float* out = (float*)d_out;
    float* ws  = (float*)d_ws;

    const int* src = ei;
    const int* dst = ei + N_EDGES;

    unsigned short* htmpb = (unsigned short*)(ws + OFF_HTMPB);
    unsigned short* obf   = (unsigned short*)(ws + OFF_OBF);
    int*   deg      = (int*)(ws + OFF_DEG);
    int*   rowstart = (int*)(ws + OFF_ROWSTART);
    int*   cursor   = (int*)(ws + OFF_CURSOR);
    float* dinv     = ws + OFF_DINV;
    float* Earr     = ws + OFF_E;
    float* scal     = ws + OFF_SCAL;
    int*   blksum   = (int*)(ws + OFF_BLKSUM);
    int*   esrc     = (int*)(ws + OFF_ESRC);

    const int NBLK = 196;  // ceil(50000/256)

    k_init<<<NBLK, 256, 0, stream>>>(ws);
    k_deg<<<N_EDGES / 256, 256, 0, stream>>>(dst, deg);
    k_gemm<<<dim3(782, 2), 256, 0, stream>>>(x, W, htmpb);
    k_scan1<<<NBLK, 256, 0, stream>>>(deg, rowstart, blksum, dinv);
    k_scan2<<<1, 256, 0, stream>>>(blksum, NBLK);
    k_scan3<<<NBLK, 256, 0, stream>>>(rowstart, blksum, cursor);
    k_bucket<<<N_EDGES / 256, 256, 0, stream>>>(src, dst, rowstart, cursor, esrc);
    k_gather<<<6250, 256, 0, stream>>>(htmpb, dinv, b, rowstart, esrc, out, obf);
    k_energy<<<6250, 256, 0, stream>>>(obf, rowstart, esrc, Earr);
    k_emin<<<NBLK, 256, 0, stream>>>(Earr, (int*)scal);
    k_sums<<<NBLK, 256, 0, stream>>>(Earr, temp, (const int*)scal, scal + 1);
    k_grad<<<6250, 256, 0, stream>>>(rowstart, esrc, Earr, temp, scal, weight, out);
}

// Round 6
// 266.348 us; speedup vs baseline: 1.6451x; 1.0753x over previous
//
#include <hip/hip_runtime.h>

#define N_NODES 50000
#define N_EDGES 640000

// workspace layout (4B units)
#define OFF_HTMPB    0          // ushort[6400000] bf16 h=xW  -> 3200000 floats
#define OFF_OBF      3200000    // ushort[6400000] bf16 copy of out
#define OFF_DEG      6400000    // int[50000]
#define OFF_ROWSTART 6450000    // int[50001]
#define OFF_CURSOR   6500016    // int[50000]
#define OFF_DINV     6550016    // float[50000]
#define OFF_E        6600016    // float[50000]
#define OFF_SCAL     6650016    // [0]=EminBits [1]=S0 [2]=S1
#define OFF_BLKSUM   6650020    // int[256]
#define OFF_ESRC     6650276    // int[640000] CSR-bucketed source ids

typedef __attribute__((ext_vector_type(4))) short bf16x4;
typedef __attribute__((ext_vector_type(8))) short bf16x8;
typedef __attribute__((ext_vector_type(4))) float f32x4;

__device__ __forceinline__ unsigned short f2bf(float f) {  // RNE
    unsigned u = __float_as_uint(f);
    unsigned r = u + 0x7fffu + ((u >> 16) & 1u);
    return (unsigned short)(r >> 16);
}
__device__ __forceinline__ float bflo(unsigned u) { return __uint_as_float(u << 16); }
__device__ __forceinline__ float bfhi(unsigned u) { return __uint_as_float(u & 0xffff0000u); }

__global__ __launch_bounds__(256) void k_init(float* ws) {
    int i = blockIdx.x * 256 + threadIdx.x;
    if (i < N_NODES) ((int*)(ws + OFF_DEG))[i] = 0;
    if (i == 0) {
        ((int*)(ws + OFF_SCAL))[0] = 0x7F7FFFFF;  // FLT_MAX bits
        ws[OFF_SCAL + 1] = 0.f;
        ws[OFF_SCAL + 2] = 0.f;
    }
}

__global__ __launch_bounds__(256) void k_deg(const int* __restrict__ dst, int* __restrict__ deg) {
    int e = blockIdx.x * 256 + threadIdx.x;
    atomicAdd(&deg[dst[e]], 1);
}

// h = x @ W via bf16 MFMA (f32 accumulate), store bf16.
// Block: 128 rows x N=128. LDS: x-tile bf16 [128][132], W^T bf16 [128][132].
// Wave w handles rows [w*32, w*32+32) as two 16-row MFMA tiles x 8 col-tiles.
__global__ __launch_bounds__(256) void k_gemm(const float* __restrict__ x,
                                              const float* __restrict__ W,
                                              unsigned short* __restrict__ htmpb) {
    __shared__ unsigned short xs[128 * 132];
    __shared__ unsigned short wt[128 * 132];
    int tid = threadIdx.x;
    int r0 = blockIdx.x * 128;

    // stage x (f32 -> bf16), coalesced float4 reads
    #pragma unroll
    for (int i = 0; i < 16; i++) {
        int slot = tid + i * 256;          // 4096 float4 slots
        int row = slot >> 5, c4 = slot & 31;
        float4 v = make_float4(0.f, 0.f, 0.f, 0.f);
        int gr = r0 + row;
        if (gr < N_NODES) v = *(const float4*)(x + gr * 128 + c4 * 4);
        uint2 pk;
        pk.x = (unsigned)f2bf(v.x) | ((unsigned)f2bf(v.y) << 16);
        pk.y = (unsigned)f2bf(v.z) | ((unsigned)f2bf(v.w) << 16);
        *(uint2*)(xs + row * 132 + c4 * 4) = pk;   // 8B-aligned
    }
    // stage W^T (f32 -> bf16): read W[k][n] coalesced, write wt[n][k]
    #pragma unroll
    for (int i = 0; i < 16; i++) {
        int slot = tid + i * 256;
        int k = slot >> 5, n4 = (slot & 31) * 4;
        float4 v = *(const float4*)(W + k * 128 + n4);
        wt[(n4 + 0) * 132 + k] = f2bf(v.x);
        wt[(n4 + 1) * 132 + k] = f2bf(v.y);
        wt[(n4 + 2) * 132 + k] = f2bf(v.z);
        wt[(n4 + 3) * 132 + k] = f2bf(v.w);
    }
    __syncthreads();

    int wave = tid >> 6, lane = tid & 63;
    int quad = lane >> 4, m16 = lane & 15;
    f32x4 acc[2][8];
    #pragma unroll
    for (int r = 0; r < 2; r++)
        #pragma unroll
        for (int c = 0; c < 8; c++) acc[r][c] = (f32x4){0.f, 0.f, 0.f, 0.f};

    int arow = wave * 32 + m16;
    #pragma unroll
    for (int kt = 0; kt < 4; kt++) {
        int koff = kt * 32 + quad * 8;
        // A frags: A[m=lane&15][k=quad*8+j], two 16-row tiles. 2x b64 loads (8B aligned).
        bf16x4 a0l = *(const bf16x4*)(xs + arow * 132 + koff);
        bf16x4 a0h = *(const bf16x4*)(xs + arow * 132 + koff + 4);
        bf16x4 a1l = *(const bf16x4*)(xs + (arow + 16) * 132 + koff);
        bf16x4 a1h = *(const bf16x4*)(xs + (arow + 16) * 132 + koff + 4);
        bf16x8 a0 = __builtin_shufflevector(a0l, a0h, 0, 1, 2, 3, 4, 5, 6, 7);
        bf16x8 a1 = __builtin_shufflevector(a1l, a1h, 0, 1, 2, 3, 4, 5, 6, 7);
        #pragma unroll
        for (int c = 0; c < 8; c++) {
            bf16x4 bl = *(const bf16x4*)(wt + (c * 16 + m16) * 132 + koff);
            bf16x4 bh = *(const bf16x4*)(wt + (c * 16 + m16) * 132 + koff + 4);
            bf16x8 bfrag = __builtin_shufflevector(bl, bh, 0, 1, 2, 3, 4, 5, 6, 7);
            acc[0][c] = __builtin_amdgcn_mfma_f32_16x16x32_bf16(a0, bfrag, acc[0][c], 0, 0, 0);
            acc[1][c] = __builtin_amdgcn_mfma_f32_16x16x32_bf16(a1, bfrag, acc[1][c], 0, 0, 0);
        }
    }
    // C/D: col = lane&15, row = quad*4 + reg
    #pragma unroll
    for (int r = 0; r < 2; r++) {
        #pragma unroll
        for (int reg = 0; reg < 4; reg++) {
            int grow = r0 + wave * 32 + r * 16 + quad * 4 + reg;
            if (grow < N_NODES) {
                #pragma unroll
                for (int c = 0; c < 8; c++)
                    htmpb[grow * 128 + c * 16 + m16] = f2bf(acc[r][c][reg]);
            }
        }
    }
}

// ---- exclusive scan of deg -> rowstart (+dinv fused) ----
__global__ __launch_bounds__(256) void k_scan1(const int* __restrict__ deg,
                                               int* __restrict__ rowstart,
                                               int* __restrict__ blksum,
                                               float* __restrict__ dinv) {
    __shared__ int sh[256];
    int i = blockIdx.x * 256 + threadIdx.x;
    int v = (i < N_NODES) ? deg[i] : 0;
    if (i < N_NODES) dinv[i] = rsqrtf((float)(v + 1));  // +1 self-loop
    sh[threadIdx.x] = v;
    __syncthreads();
    #pragma unroll
    for (int off = 1; off < 256; off <<= 1) {
        int t = (threadIdx.x >= off) ? sh[threadIdx.x - off] : 0;
        __syncthreads();
        sh[threadIdx.x] += t;
        __syncthreads();
    }
    if (i < N_NODES) rowstart[i] = sh[threadIdx.x] - v;  // exclusive
    if (threadIdx.x == 255) blksum[blockIdx.x] = sh[255];
}

__global__ __launch_bounds__(256) void k_scan2(int* __restrict__ blksum, int nblk) {
    __shared__ int sh[256];
    int tid = threadIdx.x;
    int v = (tid < nblk) ? blksum[tid] : 0;
    sh[tid] = v;
    __syncthreads();
    #pragma unroll
    for (int off = 1; off < 256; off <<= 1) {
        int t = (tid >= off) ? sh[tid - off] : 0;
        __syncthreads();
        sh[tid] += t;
        __syncthreads();
    }
    if (tid < nblk) blksum[tid] = sh[tid] - v;  // exclusive
}

__global__ __launch_bounds__(256) void k_scan3(int* __restrict__ rowstart,
                                               const int* __restrict__ blksum,
                                               int* __restrict__ cursor) {
    int i = blockIdx.x * 256 + threadIdx.x;
    if (i < N_NODES) {
        rowstart[i] += blksum[blockIdx.x];
        cursor[i] = 0;
    }
    if (i == 0) rowstart[N_NODES] = N_EDGES;
}

__global__ __launch_bounds__(256) void k_bucket(const int* __restrict__ src,
                                                const int* __restrict__ dst,
                                                const int* __restrict__ rowstart,
                                                int* __restrict__ cursor,
                                                int* __restrict__ esrc) {
    int e = blockIdx.x * 256 + threadIdx.x;
    int d = dst[e];
    int pos = atomicAdd(&cursor[d], 1);
    esrc[rowstart[d] + pos] = src[e];
}

// per node (32 lanes, 4 bf16 per lane via uint2), 2 chains:
// out[d] = b + htmp[d]*dinv[d]^2 + sum_s htmp[s]*dinv[s]*dinv[d]; also bf16 copy obf.
__global__ __launch_bounds__(256) void k_gather(const unsigned short* __restrict__ htmpb,
                                                const float* __restrict__ dinv,
                                                const float* __restrict__ b,
                                                const int* __restrict__ rowstart,
                                                const int* __restrict__ esrc,
                                                float* __restrict__ out,
                                                unsigned short* __restrict__ obf) {
    int node = blockIdx.x * 8 + (threadIdx.x >> 5);
    int lane = threadIdx.x & 31;
    float di = dinv[node];
    float4 bv = *(const float4*)(b + lane * 4);
    uint2 hv = *(const uint2*)(htmpb + node * 128 + lane * 4);
    float sl = di * di;
    float ax = bv.x + bflo(hv.x) * sl, ay = bv.y + bfhi(hv.x) * sl;
    float az = bv.z + bflo(hv.y) * sl, aw = bv.w + bfhi(hv.y) * sl;
    float cx = 0.f, cy = 0.f, cz = 0.f, cw = 0.f;
    int e0 = rowstart[node], e1 = rowstart[node + 1];
    int k = e0;
    for (; k + 1 < e1; k += 2) {
        int s0 = esrc[k], s1 = esrc[k + 1];
        float n0 = di * dinv[s0], n1 = di * dinv[s1];
        uint2 u0 = *(const uint2*)(htmpb + s0 * 128 + lane * 4);
        uint2 u1 = *(const uint2*)(htmpb + s1 * 128 + lane * 4);
        ax += bflo(u0.x) * n0; ay += bfhi(u0.x) * n0;
        az += bflo(u0.y) * n0; aw += bfhi(u0.y) * n0;
        cx += bflo(u1.x) * n1; cy += bfhi(u1.x) * n1;
        cz += bflo(u1.y) * n1; cw += bfhi(u1.y) * n1;
    }
    if (k < e1) {
        int s0 = esrc[k];
        float n0 = di * dinv[s0];
        uint2 u0 = *(const uint2*)(htmpb + s0 * 128 + lane * 4);
        ax += bflo(u0.x) * n0; ay += bfhi(u0.x) * n0;
        az += bflo(u0.y) * n0; aw += bfhi(u0.y) * n0;
    }
    ax += cx; ay += cy; az += cz; aw += cw;
    *(float4*)(out + node * 128 + lane * 4) = make_float4(ax, ay, az, aw);
    uint2 pk;
    pk.x = (unsigned)f2bf(ax) | ((unsigned)f2bf(ay) << 16);
    pk.y = (unsigned)f2bf(az) | ((unsigned)f2bf(aw) << 16);
    *(uint2*)(obf + node * 128 + lane * 4) = pk;
}

// per node: E[d] = sum_{edges into d} ||out[s]-out[d]||^2 from bf16 copy, 2 chains.
__global__ __launch_bounds__(256) void k_energy(const unsigned short* __restrict__ obf,
                                                const int* __restrict__ rowstart,
                                                const int* __restrict__ esrc,
                                                float* __restrict__ E) {
    int node = blockIdx.x * 8 + (threadIdx.x >> 5);
    int lane = threadIdx.x & 31;
    uint2 ud = *(const uint2*)(obf + node * 128 + lane * 4);
    float o0 = bflo(ud.x), o1 = bfhi(ud.x), o2 = bflo(ud.y), o3 = bfhi(ud.y);
    float acc = 0.f, acc2 = 0.f;
    int e0 = rowstart[node], e1 = rowstart[node + 1];
    int k = e0;
    for (; k + 1 < e1; k += 2) {
        int s0 = esrc[k], s1 = esrc[k + 1];
        uint2 a = *(const uint2*)(obf + s0 * 128 + lane * 4);
        uint2 c = *(const uint2*)(obf + s1 * 128 + lane * 4);
        float d0 = bflo(a.x) - o0, d1 = bfhi(a.x) - o1;
        float d2 = bflo(a.y) - o2, d3 = bfhi(a.y) - o3;
        float e4 = bflo(c.x) - o0, e5 = bfhi(c.x) - o1;
        float e6 = bflo(c.y) - o2, e7 = bfhi(c.y) - o3;
        acc  += d0 * d0 + d1 * d1 + d2 * d2 + d3 * d3;
        acc2 += e4 * e4 + e5 * e5 + e6 * e6 + e7 * e7;
    }
    if (k < e1) {
        int s0 = esrc[k];
        uint2 a = *(const uint2*)(obf + s0 * 128 + lane * 4);
        float d0 = bflo(a.x) - o0, d1 = bfhi(a.x) - o1;
        float d2 = bflo(a.y) - o2, d3 = bfhi(a.y) - o3;
        acc += d0 * d0 + d1 * d1 + d2 * d2 + d3 * d3;
    }
    acc += acc2;
    #pragma unroll
    for (int off = 16; off; off >>= 1) acc += __shfl_xor(acc, off);
    if (lane == 0) E[node] = acc;
}

__global__ __launch_bounds__(256) void k_emin(const float* __restrict__ E, int* __restrict__ scal) {
    __shared__ float sh[4];
    int i = blockIdx.x * 256 + threadIdx.x;
    float v = 3.402823466e38f;
    if (i < N_NODES) v = E[i];
    #pragma unroll
    for (int off = 32; off; off >>= 1) v = fminf(v, __shfl_xor(v, off));
    int lane = threadIdx.x & 63, wid = threadIdx.x >> 6;
    if (lane == 0) sh[wid] = v;
    __syncthreads();
    if (threadIdx.x == 0) {
        float m = fminf(fminf(sh[0], sh[1]), fminf(sh[2], sh[3]));
        atomicMin(scal, __float_as_int(m));  // valid: E >= 0
    }
}

__global__ __launch_bounds__(256) void k_sums(const float* __restrict__ E,
                                              const float* __restrict__ temp,
                                              const int* __restrict__ scal,
                                              float* __restrict__ S) {
    __shared__ float sh0[4], sh1[4];
    float Emin = __int_as_float(scal[0]);
    float T = temp[0];
    int i = blockIdx.x * 256 + threadIdx.x;
    float s0 = 0.f, s1 = 0.f;
    if (i < N_NODES) {
        float dd = (Emin - E[i]) / T;
        float ed = __expf(dd);
        s0 = ed; s1 = ed * dd;
    }
    #pragma unroll
    for (int off = 32; off; off >>= 1) { s0 += __shfl_xor(s0, off); s1 += __shfl_xor(s1, off); }
    int lane = threadIdx.x & 63, wid = threadIdx.x >> 6;
    if (lane == 0) { sh0[wid] = s0; sh1[wid] = s1; }
    __syncthreads();
    if (threadIdx.x == 0) {
        atomicAdd(&S[0], sh0[0] + sh0[1] + sh0[2] + sh0[3]);
        atomicAdd(&S[1], sh1[0] + sh1[1] + sh1[2] + sh1[3]);
    }
}

// CSR-driven gradient with inline q (f32 out path): skip q==0 nodes (almost all).
__global__ __launch_bounds__(256) void k_grad(const int* __restrict__ rowstart,
                                              const int* __restrict__ esrc,
                                              const float* __restrict__ E,
                                              const float* __restrict__ temp,
                                              const float* __restrict__ scal,
                                              const float* __restrict__ weight,
                                              float* __restrict__ out) {
    int node = blockIdx.x * 8 + (threadIdx.x >> 5);
    int lane = threadIdx.x & 31;
    float Emin = __int_as_float(((const int*)scal)[0]);
    float S0 = scal[1], S1 = scal[2];
    float T = temp[0];
    float dd = (Emin - E[node]) / T;
    float qd = (__expf(dd) / S0) * (dd - S1 / S0) / T;
    if (qd == 0.f) return;
    float cc = 2.f * weight[0] * qd;
    float4 od = *(const float4*)(out + node * 128 + lane * 4);
    float sx = 0.f, sy = 0.f, sz = 0.f, sw = 0.f;
    int e0 = rowstart[node], e1 = rowstart[node + 1];
    for (int k = e0; k < e1; k++) {
        int s = esrc[k];
        float4 a = *(const float4*)(out + s * 128 + lane * 4);
        float vx = cc * (a.x - od.x), vy = cc * (a.y - od.y);
        float vz = cc * (a.z - od.z), vw = cc * (a.w - od.w);
        float* os = out + s * 128 + lane * 4;
        atomicAdd(os + 0, vx); atomicAdd(os + 1, vy);
        atomicAdd(os + 2, vz); atomicAdd(os + 3, vw);
        sx += vx; sy += vy; sz += vz; sw += vw;
    }
    float* odp = out + node * 128 + lane * 4;
    atomicAdd(odp + 0, -sx); atomicAdd(odp + 1, -sy);
    atomicAdd(odp + 2, -sz); atomicAdd(odp + 3, -sw);
}

extern "C" void kernel_launch(void* const* d_in, const int* in_sizes, int n_in,
                              void* d_out, int out_size, void* d_ws, size_t ws_size,
                              hipStream_t stream) {
    const float* x      = (const float*)d_in[0];
    const int*   ei     = (const int*)d_in[1];
    const float* weight = (const float*)d_in[2];
    const float* temp   = (const float*)d_in[3];
    const float* W      = (const float*)d_in[4];
    const float* b      = (const float*)d_in[5];
    float* out = (float*)d_out;
    float* ws  = (float*)d_ws;

    const int* src = ei;
    const int* dst = ei + N_EDGES;

    unsigned short* htmpb = (unsigned short*)(ws + OFF_HTMPB);
    unsigned short* obf   = (unsigned short*)(ws + OFF_OBF);
    int*   deg      = (int*)(ws + OFF_DEG);
    int*   rowstart = (int*)(ws + OFF_ROWSTART);
    int*   cursor   = (int*)(ws + OFF_CURSOR);
    float* dinv     = ws + OFF_DINV;
    float* Earr     = ws + OFF_E;
    float* scal     = ws + OFF_SCAL;
    int*   blksum   = (int*)(ws + OFF_BLKSUM);
    int*   esrc     = (int*)(ws + OFF_ESRC);

    const int NBLK = 196;  // ceil(50000/256)

    k_init<<<NBLK, 256, 0, stream>>>(ws);
    k_deg<<<N_EDGES / 256, 256, 0, stream>>>(dst, deg);
    k_gemm<<<391, 256, 0, stream>>>(x, W, htmpb);   // ceil(50000/128)
    k_scan1<<<NBLK, 256, 0, stream>>>(deg, rowstart, blksum, dinv);
    k_scan2<<<1, 256, 0, stream>>>(blksum, NBLK);
    k_scan3<<<NBLK, 256, 0, stream>>>(rowstart, blksum, cursor);
    k_bucket<<<N_EDGES / 256, 256, 0, stream>>>(src, dst, rowstart, cursor, esrc);
    k_gather<<<6250, 256, 0, stream>>>(htmpb, dinv, b, rowstart, esrc, out, obf);
    k_energy<<<6250, 256, 0, stream>>>(obf, rowstart, esrc, Earr);
    k_emin<<<NBLK, 256, 0, stream>>>(Earr, (int*)scal);
    k_sums<<<NBLK, 256, 0, stream>>>(Earr, temp, (const int*)scal, scal + 1);
    k_grad<<<6250, 256, 0, stream>>>(rowstart, esrc, Earr, temp, scal, weight, out);
}